// Round 2
// baseline (350.164 us; speedup 1.0000x reference)
//
#include <hip/hip_runtime.h>

#define NN 100000
#define NE 3200000
#define F 64
#define NR 8
#define PAD 34                 // LDS row stride (floats) for 32-node As
#define NCB 98                 // coarse buckets = ceil(NN/1024), bucket = dst>>10
#define CAPC 36864             // capacity per coarse bucket
#define CHUNKA 4000            // edges per binA block (800 blocks)
#define NT 3125                // node tiles = NN/32 (exact: 3125*32 = 100000)
#define SLCAP 1280             // per-tile edge list capacity (mean 1024, +8 sigma)

// ---------------- init: per-coarse-bucket staging cursors -------------------
__global__ __launch_bounds__(128) void init_kernel(int* __restrict__ cursors) {
    int t = threadIdx.x;
    if (t < NCB) cursors[t] = t * CAPC;
}

// ---------------- pass A: coarse-bin edges (4-copy LDS multi-split) ---------
__global__ __launch_bounds__(256) void binA_kernel(
    const int* __restrict__ esrc, const int* __restrict__ edst,
    const int* __restrict__ etyp,
    int* __restrict__ cursors, uint2* __restrict__ stag8)
{
    __shared__ int hist[128][4];
    __shared__ int start[128];
    __shared__ int cur[128][4];
    __shared__ int gbase[NCB];
    __shared__ uint2 recs[CHUNKA];   // 32 KB

    const int t = threadIdx.x;
    const int cp = t & 3;
    const int e0 = blockIdx.x * CHUNKA;

    if (t < 128) ((int4*)hist)[t] = make_int4(0, 0, 0, 0);
    __syncthreads();

    uint2 rec[16];
#pragma unroll
    for (int j = 0; j < 16; j++) {
        int i = t + j * 256;
        if (i < CHUNKA) {
            int e = e0 + i;
            unsigned s = (unsigned)esrc[e];
            unsigned d = (unsigned)edst[e];
            unsigned r = (unsigned)etyp[e];
            rec[j] = make_uint2(s, d | (r << 17));
            atomicAdd(&hist[d >> 10][cp], 1);
        }
    }
    __syncthreads();

    int tot = 0;
    if (t < 128) {
        int4 h4 = ((int4*)hist)[t];
        tot = h4.x + h4.y + h4.z + h4.w;
        start[t] = tot;
    }
    __syncthreads();
    for (int off = 1; off < 128; off <<= 1) {
        int v = 0;
        if (t < 128 && t >= off) v = start[t - off];
        __syncthreads();
        if (t < 128) start[t] += v;
        __syncthreads();
    }
    if (t < 128) start[t] -= tot;   // inclusive -> exclusive
    __syncthreads();
    if (t < NCB) {
        int4 h4 = ((int4*)hist)[t];
        int s = start[t];
        cur[t][0] = s;
        cur[t][1] = s + h4.x;
        cur[t][2] = s + h4.x + h4.y;
        cur[t][3] = s + h4.x + h4.y + h4.z;
        gbase[t] = atomicAdd(&cursors[t], tot);
    }
    __syncthreads();

#pragma unroll
    for (int j = 0; j < 16; j++) {
        int i = t + j * 256;
        if (i < CHUNKA) {
            int b = (int)((rec[j].y & 0x1FFFFu) >> 10);
            int slot = atomicAdd(&cur[b][cp], 1);
            recs[slot] = rec[j];
        }
    }
    __syncthreads();

#pragma unroll
    for (int j = 0; j < 16; j++) {
        int i = t + j * 256;
        if (i < CHUNKA) {
            uint2 rr = recs[i];
            int b = (int)((rr.y & 0x1FFFFu) >> 10);
            stag8[gbase[b] + (i - start[b])] = rr;
        }
    }
}

// ---------------- pass B: fine-bin to 32-node buckets, 8 chunks/coarse ------
__global__ __launch_bounds__(256) void binB_kernel(
    const uint2* __restrict__ stag8, const int* __restrict__ cursors,
    unsigned* __restrict__ packed4, unsigned* __restrict__ runsd)
{
    __shared__ int h[32][4];
    __shared__ int cu[32][4];
    const int b = blockIdx.x >> 3;
    const int c = blockIdx.x & 7;
    const int t = threadIdx.x;
    const int cp = t & 3;
    const int bbase = b * CAPC;
    const int n = cursors[b] - bbase;
    const int s = (int)(((long long)c * n) >> 3);
    const int e = (int)(((long long)(c + 1) * n) >> 3);
    const int base = bbase + s;
    const int cn = e - s;

    if (t < 128) ((int*)h)[t] = 0;
    __syncthreads();
    for (int i = t; i < cn; i += 256) {
        unsigned y = stag8[base + i].y;
        atomicAdd(&h[(y >> 5) & 31][cp], 1);
    }
    __syncthreads();
    if (t == 0) {
        int acc = 0;
        for (int f = 0; f < 32; f++) {
            int fstart = acc;
#pragma unroll
            for (int k = 0; k < 4; k++) { cu[f][k] = acc; acc += h[f][k]; }
            runsd[(blockIdx.x << 5) + f] = ((unsigned)(base + fstart) << 10) | (unsigned)(acc - fstart);
        }
    }
    __syncthreads();
    for (int i = t; i < cn; i += 256) {
        uint2 rr = stag8[base + i];
        unsigned f = (rr.y >> 5) & 31u;
        int p = atomicAdd(&cu[f][cp], 1);
        unsigned d = rr.y & 0x1FFFFu;
        unsigned r = rr.y >> 17;
        // key8 = r*32 + (d&31) lives in bits [17..24] -> fused key = p>>17
        packed4[base + p] = rr.x | ((d & 31u) << 17) | (r << 22);
    }
}

// ---------------- fused: sort + gather + GEMM, 32-node tiles, all-resident --
// Round-2 change: the 33% occupancy / 132us drain tail (283 leftover blocks at
// 1 wave/SIMD) was the bottleneck, not barriers. Fix: 32-node tiles (3125
// blocks x 128 thr) and slist moved to global scratch (aliases dead stag8).
// LDS ~9.8 KB -> 14-16 blocks/CU -> the ENTIRE grid is co-resident; no drain
// phase, 7-8 waves/SIMD of TLP for the whole kernel.
__global__ __launch_bounds__(128) void fused_kernel(
    const float* __restrict__ x,
    const unsigned* __restrict__ packed4,
    const unsigned* __restrict__ runsd,
    int* __restrict__ slg,              // global per-tile sorted src lists
    const float* __restrict__ weight,   // [8][64][64]
    const float* __restrict__ root,     // [64][64]
    const float* __restrict__ bias,
    float* __restrict__ out)
{
    __shared__ __align__(16) float As[64][PAD];  // As[k][node], 8.7 KB
    __shared__ int kstart[257];                  // run starts; [256] = total
    __shared__ unsigned rdesc[8];
    __shared__ int wsum[2];
    int* const kcur = (int*)&As[0][0];   // overlay: dead until staging begins

    const int t = threadIdx.x;
    const int tile = blockIdx.x;
    const int lane = t & 63;
    const int wid = t >> 6;
    int* const myslist = slg + (size_t)tile * SLCAP;

    if (t < 8) rdesc[t] = runsd[(((tile >> 5) * 8 + t) << 5) + (tile & 31)];
    kstart[t] = 0; kstart[t + 128] = 0;
    __syncthreads();

    // ---- hist by key8 = rel*32 + dstLow5 over the 8 chunk-runs ----
#pragma unroll
    for (int c = 0; c < 8; c++) {
        unsigned d = rdesc[c];
        int rs = (int)(d >> 10), rc = (int)(d & 1023u);
        for (int i = t; i < rc; i += 128)
            atomicAdd(&kstart[packed4[rs + i] >> 17], 1);
    }
    __syncthreads();

    // ---- exclusive scan of 256 counts: 2 keys/thread, wave shfl scan ----
    const int a0 = kstart[2 * t], a1 = kstart[2 * t + 1];
    int v = a0 + a1;
#pragma unroll
    for (int off = 1; off < 64; off <<= 1) {
        int u = __shfl_up(v, off);
        if (lane >= off) v += u;
    }
    if (lane == 63) wsum[wid] = v;
    __syncthreads();                       // orders kstart reads vs writes below
    const int wo = wid ? wsum[0] : 0;
    const int incl = wo + v;
    const int ebase = incl - a0 - a1;
    kstart[2 * t]     = ebase;
    kstart[2 * t + 1] = ebase + a0;
    kcur[2 * t]       = ebase;
    kcur[2 * t + 1]   = ebase + a0;
    if (t == 127) kstart[256] = incl;      // total edge count
    __syncthreads();

    // ---- scatter into per-key runs (global slist; tile range is L1/L2-hot) --
#pragma unroll
    for (int c = 0; c < 8; c++) {
        unsigned d = rdesc[c];
        int rs = (int)(d >> 10), rc = (int)(d & 1023u);
        for (int i = t; i < rc; i += 128) {
            unsigned p = packed4[rs + i];
            int slot = atomicAdd(&kcur[p >> 17], 1);
            myslist[slot] = (int)(p & 0x1FFFFu);   // src only; runs per-key
        }
    }
    __syncthreads();   // LAST barrier: slist/kstart frozen, kcur (As) dead

    // ---- per-wave pipeline over 9 segs, barrier-free ----
    const int node0 = tile * 32;
    const int w16 = wid << 4;             // wave's 16-column slice of As
    const int sn  = w16 + (lane >> 2);    // As column / node within tile
    const int sq  = lane & 3;             // k-quarter 0..3
    const int k0  = sq << 2;
    const int tx  = lane & 15;            // fout group
    const int tyw = lane >> 4;            // node quad within wave 0..3
    const int acol = w16 + (tyw << 2);

    float acc[4][4];
#pragma unroll
    for (int i = 0; i < 4; i++)
#pragma unroll
        for (int j = 0; j < 4; j++) acc[i][j] = 0.f;

    for (int seg = 0; seg < 9; seg++) {
        const float* __restrict__ Wseg = (seg == 0) ? root : (weight + (size_t)(seg - 1) * (F * F));

        if (seg == 0) {
            // root: stage own-row x (transposed into As); all tiles full (NN%32==0)
            const float* rowp = x + (size_t)(node0 + sn) * F;
#pragma unroll
            for (int j = 0; j < 4; j++) {
                int kc = k0 + 16 * j;
                float4 vv = *(const float4*)(rowp + kc);
                As[kc + 0][sn] = vv.x;
                As[kc + 1][sn] = vv.y;
                As[kc + 2][sn] = vv.z;
                As[kc + 3][sn] = vv.w;
            }
        } else {
            // mean-gather this wave's 16 nodes for relation seg-1
            const int key = ((seg - 1) << 5) | sn;
            const int beg = kstart[key];
            const int end = kstart[key + 1];   // prefix property: next start
            float4 a0v = make_float4(0.f, 0.f, 0.f, 0.f);
            float4 a1v = a0v, a2v = a0v, a3v = a0v;
            int i = beg;
            for (; i + 2 <= end; i += 2) {     // 2-edge unroll: 8 loads in flight
                const float* xr0 = x + (size_t)myslist[i] * F + k0;
                const float* xr1 = x + (size_t)myslist[i + 1] * F + k0;
                float4 u0 = *(const float4*)(xr0);
                float4 u1 = *(const float4*)(xr0 + 16);
                float4 u2 = *(const float4*)(xr0 + 32);
                float4 u3 = *(const float4*)(xr0 + 48);
                float4 p0 = *(const float4*)(xr1);
                float4 p1 = *(const float4*)(xr1 + 16);
                float4 p2 = *(const float4*)(xr1 + 32);
                float4 p3 = *(const float4*)(xr1 + 48);
                a0v.x += u0.x + p0.x; a0v.y += u0.y + p0.y; a0v.z += u0.z + p0.z; a0v.w += u0.w + p0.w;
                a1v.x += u1.x + p1.x; a1v.y += u1.y + p1.y; a1v.z += u1.z + p1.z; a1v.w += u1.w + p1.w;
                a2v.x += u2.x + p2.x; a2v.y += u2.y + p2.y; a2v.z += u2.z + p2.z; a2v.w += u2.w + p2.w;
                a3v.x += u3.x + p3.x; a3v.y += u3.y + p3.y; a3v.z += u3.z + p3.z; a3v.w += u3.w + p3.w;
            }
            if (i < end) {
                const float* xr0 = x + (size_t)myslist[i] * F + k0;
                float4 u0 = *(const float4*)(xr0);
                float4 u1 = *(const float4*)(xr0 + 16);
                float4 u2 = *(const float4*)(xr0 + 32);
                float4 u3 = *(const float4*)(xr0 + 48);
                a0v.x += u0.x; a0v.y += u0.y; a0v.z += u0.z; a0v.w += u0.w;
                a1v.x += u1.x; a1v.y += u1.y; a1v.z += u1.z; a1v.w += u1.w;
                a2v.x += u2.x; a2v.y += u2.y; a2v.z += u2.z; a2v.w += u2.w;
                a3v.x += u3.x; a3v.y += u3.y; a3v.z += u3.z; a3v.w += u3.w;
            }
            const float scl = 1.0f / (float)max(end - beg, 1);
            As[k0 +  0][sn] = a0v.x * scl; As[k0 +  1][sn] = a0v.y * scl;
            As[k0 +  2][sn] = a0v.z * scl; As[k0 +  3][sn] = a0v.w * scl;
            As[k0 + 16][sn] = a1v.x * scl; As[k0 + 17][sn] = a1v.y * scl;
            As[k0 + 18][sn] = a1v.z * scl; As[k0 + 19][sn] = a1v.w * scl;
            As[k0 + 32][sn] = a2v.x * scl; As[k0 + 33][sn] = a2v.y * scl;
            As[k0 + 34][sn] = a2v.z * scl; As[k0 + 35][sn] = a2v.w * scl;
            As[k0 + 48][sn] = a3v.x * scl; As[k0 + 49][sn] = a3v.y * scl;
            As[k0 + 50][sn] = a3v.z * scl; As[k0 + 51][sn] = a3v.w * scl;
        }

        // wave-local GEMM: reads only this wave's 16 columns (same-wave LDS
        // RAW, in-order -> no barrier). b rows straight from global (L1-hot).
#pragma unroll 8
        for (int k = 0; k < 64; k++) {
            float4 a = *(const float4*)&As[k][acol];
            float4 b = *(const float4*)(Wseg + (k << 6) + (tx << 2));
            acc[0][0] = fmaf(a.x, b.x, acc[0][0]);
            acc[0][1] = fmaf(a.x, b.y, acc[0][1]);
            acc[0][2] = fmaf(a.x, b.z, acc[0][2]);
            acc[0][3] = fmaf(a.x, b.w, acc[0][3]);
            acc[1][0] = fmaf(a.y, b.x, acc[1][0]);
            acc[1][1] = fmaf(a.y, b.y, acc[1][1]);
            acc[1][2] = fmaf(a.y, b.z, acc[1][2]);
            acc[1][3] = fmaf(a.y, b.w, acc[1][3]);
            acc[2][0] = fmaf(a.z, b.x, acc[2][0]);
            acc[2][1] = fmaf(a.z, b.y, acc[2][1]);
            acc[2][2] = fmaf(a.z, b.z, acc[2][2]);
            acc[2][3] = fmaf(a.z, b.w, acc[2][3]);
            acc[3][0] = fmaf(a.w, b.x, acc[3][0]);
            acc[3][1] = fmaf(a.w, b.y, acc[3][1]);
            acc[3][2] = fmaf(a.w, b.z, acc[3][2]);
            acc[3][3] = fmaf(a.w, b.w, acc[3][3]);
        }
    }

    // epilogue: + bias, coalesced float4 stores (wave-private, no barrier)
    float4 bv = *(const float4*)(bias + (tx << 2));
#pragma unroll
    for (int i = 0; i < 4; i++) {
        int node = node0 + w16 + (tyw << 2) + i;   // always < NN (NN%32==0)
        float4 o = make_float4(acc[i][0] + bv.x, acc[i][1] + bv.y,
                               acc[i][2] + bv.z, acc[i][3] + bv.w);
        *(float4*)(out + (size_t)node * F + (tx << 2)) = o;
    }
}

extern "C" void kernel_launch(void* const* d_in, const int* in_sizes, int n_in,
                              void* d_out, int out_size, void* d_ws, size_t ws_size,
                              hipStream_t stream) {
    const float* x    = (const float*)d_in[0];
    const int*   ei   = (const int*)d_in[1];
    const int*   et   = (const int*)d_in[2];
    const float* wgt  = (const float*)d_in[3];
    const float* root = (const float*)d_in[4];
    const float* bias = (const float*)d_in[5];
    float*       out  = (float*)d_out;

    int*      cursors = (int*)d_ws;                                   // [128]
    unsigned* runsd   = (unsigned*)((char*)d_ws + 512);               // [784*32]
    uint2*    stag8   = (uint2*)((char*)d_ws + 512 + 100352);         // 28.9 MB
    unsigned* packed4 = (unsigned*)(stag8 + (size_t)NCB * CAPC);      // 14.5 MB
    int*      slg     = (int*)stag8;   // aliases stag8: dead after binB (16 MB)

    init_kernel<<<1, 128, 0, stream>>>(cursors);
    binA_kernel<<<NE / CHUNKA, 256, 0, stream>>>(ei, ei + NE, et, cursors, stag8);
    binB_kernel<<<NCB * 8, 256, 0, stream>>>(stag8, cursors, packed4, runsd);
    fused_kernel<<<NT, 128, 0, stream>>>(x, packed4, runsd, slg, wgt, root, bias, out);
}

// Round 3
// 326.941 us; speedup vs baseline: 1.0710x; 1.0710x over previous
//
#include <hip/hip_runtime.h>

#define NN 100000
#define NE 3200000
#define F 64
#define NR 8
#define PAD 34                 // LDS row stride (floats) for 32-node As
#define NCB 98                 // coarse buckets = ceil(NN/1024), bucket = dst>>10
#define CAPC 36864             // capacity per coarse bucket
#define CHUNKA 4000            // edges per binA block (800 blocks)
#define NT 3125                // node tiles = NN/32 (exact: 3125*32 = 100000)
#define SLCAP 1280             // per-tile edge list capacity (mean 1024, +8 sigma)

// ---------------- init: per-coarse-bucket staging cursors -------------------
__global__ __launch_bounds__(128) void init_kernel(int* __restrict__ cursors) {
    int t = threadIdx.x;
    if (t < NCB) cursors[t] = t * CAPC;
}

// ---------------- pass A: coarse-bin edges (4-copy LDS multi-split) ---------
// Round-3 change: global staging record is u32 (src17|dstLow10<<17|rel<<27),
// halving binA write + binB read traffic. LDS recs stay uint2 (need full dst
// for the bucket in the store phase).
__global__ __launch_bounds__(256) void binA_kernel(
    const int* __restrict__ esrc, const int* __restrict__ edst,
    const int* __restrict__ etyp,
    int* __restrict__ cursors, unsigned* __restrict__ stag4)
{
    __shared__ int hist[128][4];
    __shared__ int start[128];
    __shared__ int cur[128][4];
    __shared__ int gbase[NCB];
    __shared__ uint2 recs[CHUNKA];   // 32 KB

    const int t = threadIdx.x;
    const int cp = t & 3;
    const int e0 = blockIdx.x * CHUNKA;

    if (t < 128) ((int4*)hist)[t] = make_int4(0, 0, 0, 0);
    __syncthreads();

    uint2 rec[16];
#pragma unroll
    for (int j = 0; j < 16; j++) {
        int i = t + j * 256;
        if (i < CHUNKA) {
            int e = e0 + i;
            unsigned s = (unsigned)esrc[e];
            unsigned d = (unsigned)edst[e];
            unsigned r = (unsigned)etyp[e];
            rec[j] = make_uint2(s, d | (r << 17));
            atomicAdd(&hist[d >> 10][cp], 1);
        }
    }
    __syncthreads();

    int tot = 0;
    if (t < 128) {
        int4 h4 = ((int4*)hist)[t];
        tot = h4.x + h4.y + h4.z + h4.w;
        start[t] = tot;
    }
    __syncthreads();
    for (int off = 1; off < 128; off <<= 1) {
        int v = 0;
        if (t < 128 && t >= off) v = start[t - off];
        __syncthreads();
        if (t < 128) start[t] += v;
        __syncthreads();
    }
    if (t < 128) start[t] -= tot;   // inclusive -> exclusive
    __syncthreads();
    if (t < NCB) {
        int4 h4 = ((int4*)hist)[t];
        int s = start[t];
        cur[t][0] = s;
        cur[t][1] = s + h4.x;
        cur[t][2] = s + h4.x + h4.y;
        cur[t][3] = s + h4.x + h4.y + h4.z;
        gbase[t] = atomicAdd(&cursors[t], tot);
    }
    __syncthreads();

#pragma unroll
    for (int j = 0; j < 16; j++) {
        int i = t + j * 256;
        if (i < CHUNKA) {
            int b = (int)((rec[j].y & 0x1FFFFu) >> 10);
            int slot = atomicAdd(&cur[b][cp], 1);
            recs[slot] = rec[j];
        }
    }
    __syncthreads();

#pragma unroll
    for (int j = 0; j < 16; j++) {
        int i = t + j * 256;
        if (i < CHUNKA) {
            uint2 rr = recs[i];
            int b = (int)((rr.y & 0x1FFFFu) >> 10);
            unsigned d10 = rr.y & 1023u;          // low 10 bits of dst
            unsigned r   = rr.y >> 17;
            stag4[gbase[b] + (i - start[b])] = rr.x | (d10 << 17) | (r << 27);
        }
    }
}

// ---------------- pass B: fine-bin to 32-node buckets, 8 chunks/coarse ------
__global__ __launch_bounds__(256) void binB_kernel(
    const unsigned* __restrict__ stag4, const int* __restrict__ cursors,
    unsigned* __restrict__ packed4, unsigned* __restrict__ runsd)
{
    __shared__ int h[32][4];
    __shared__ int cu[32][4];
    const int b = blockIdx.x >> 3;
    const int c = blockIdx.x & 7;
    const int t = threadIdx.x;
    const int cp = t & 3;
    const int bbase = b * CAPC;
    const int n = cursors[b] - bbase;
    const int s = (int)(((long long)c * n) >> 3);
    const int e = (int)(((long long)(c + 1) * n) >> 3);
    const int base = bbase + s;
    const int cn = e - s;

    if (t < 128) ((int*)h)[t] = 0;
    __syncthreads();
    for (int i = t; i < cn; i += 256) {
        unsigned v = stag4[base + i];
        atomicAdd(&h[(v >> 22) & 31][cp], 1);   // (dstLow10 >> 5) & 31
    }
    __syncthreads();
    if (t == 0) {
        int acc = 0;
        for (int f = 0; f < 32; f++) {
            int fstart = acc;
#pragma unroll
            for (int k = 0; k < 4; k++) { cu[f][k] = acc; acc += h[f][k]; }
            runsd[(blockIdx.x << 5) + f] = ((unsigned)(base + fstart) << 10) | (unsigned)(acc - fstart);
        }
    }
    __syncthreads();
    for (int i = t; i < cn; i += 256) {
        unsigned v = stag4[base + i];
        unsigned f = (v >> 22) & 31u;
        int p = atomicAdd(&cu[f][cp], 1);
        unsigned d5  = (v >> 17) & 31u;   // dst low 5 bits
        unsigned rel = v >> 27;
        // key8 = rel*32 + (d&31) lives in bits [17..24] -> fused key = p>>17
        packed4[base + p] = (v & 0x1FFFFu) | (d5 << 17) | (rel << 22);
    }
}

// ---------------- fused: sort + gather + GEMM, 32-node tiles ----------------
// Round-3 changes: (1) slist back in LDS -- round 2's global slist added a
// dependent idx->row global latency hop in the inner gather and 24 MB of HBM
// round-trip for zero benefit. (2) 4-edge-unrolled gather: a typical
// (node,rel) list (Poisson mean 4, wave-max ~10) completes in 1-2 latency
// rounds with 16 row-loads in flight, instead of ~5 rounds at 2-deep.
// (3) packed4 register-cached from hist phase -> scatter re-read eliminated.
// LDS ~15 KB -> 8-10 blocks/CU.
__global__ __launch_bounds__(128, 4) void fused_kernel(
    const float* __restrict__ x,
    const unsigned* __restrict__ packed4,
    const unsigned* __restrict__ runsd,
    const float* __restrict__ weight,   // [8][64][64]
    const float* __restrict__ root,     // [64][64]
    const float* __restrict__ bias,
    float* __restrict__ out)
{
    __shared__ __align__(16) float As[64][PAD];  // As[k][node], 8.7 KB
    __shared__ int kstart[257];                  // run starts; [256] = total
    __shared__ int slist[SLCAP];                 // 5 KB
    __shared__ unsigned rdesc[8];
    __shared__ int wsum[2];
    int* const kcur = (int*)&As[0][0];   // overlay: dead until staging begins

    const int t = threadIdx.x;
    const int tile = blockIdx.x;
    const int lane = t & 63;
    const int wid = t >> 6;

    if (t < 8) rdesc[t] = runsd[(((tile >> 5) * 8 + t) << 5) + (tile & 31)];
    kstart[t] = 0; kstart[t + 128] = 0;
    __syncthreads();

    // ---- hist by key8 = rel*32 + dstLow5; register-cache first iteration ----
    unsigned pc[8];
#pragma unroll
    for (int c = 0; c < 8; c++) {
        unsigned d = rdesc[c];
        int rs = (int)(d >> 10), rc = (int)(d & 1023u);
        if (t < rc) {
            pc[c] = packed4[rs + t];
            atomicAdd(&kstart[pc[c] >> 17], 1);
        }
        for (int i = t + 128; i < rc; i += 128)          // rare (rc > 128)
            atomicAdd(&kstart[packed4[rs + i] >> 17], 1);
    }
    __syncthreads();

    // ---- exclusive scan of 256 counts: 2 keys/thread, wave shfl scan ----
    const int a0 = kstart[2 * t], a1 = kstart[2 * t + 1];
    int v = a0 + a1;
#pragma unroll
    for (int off = 1; off < 64; off <<= 1) {
        int u = __shfl_up(v, off);
        if (lane >= off) v += u;
    }
    if (lane == 63) wsum[wid] = v;
    __syncthreads();                       // orders kstart reads vs writes below
    const int wo = wid ? wsum[0] : 0;
    const int incl = wo + v;
    const int ebase = incl - a0 - a1;
    kstart[2 * t]     = ebase;
    kstart[2 * t + 1] = ebase + a0;
    kcur[2 * t]       = ebase;
    kcur[2 * t + 1]   = ebase + a0;
    if (t == 127) kstart[256] = incl;      // total edge count
    __syncthreads();

    // ---- scatter into per-key runs (LDS slist; packed4 from registers) ----
#pragma unroll
    for (int c = 0; c < 8; c++) {
        unsigned d = rdesc[c];
        int rs = (int)(d >> 10), rc = (int)(d & 1023u);
        if (t < rc) {
            int slot = atomicAdd(&kcur[pc[c] >> 17], 1);
            slist[slot] = (int)(pc[c] & 0x1FFFFu);
        }
        for (int i = t + 128; i < rc; i += 128) {        // rare (rc > 128)
            unsigned p = packed4[rs + i];
            int slot = atomicAdd(&kcur[p >> 17], 1);
            slist[slot] = (int)(p & 0x1FFFFu);
        }
    }
    __syncthreads();   // LAST barrier: slist/kstart frozen, kcur (As) dead

    // ---- per-wave pipeline over 9 segs, barrier-free ----
    const int node0 = tile * 32;
    const int w16 = wid << 4;             // wave's 16-column slice of As
    const int sn  = w16 + (lane >> 2);    // As column / node within tile
    const int sq  = lane & 3;             // k-quarter 0..3
    const int k0  = sq << 2;
    const int tx  = lane & 15;            // fout group
    const int tyw = lane >> 4;            // node quad within wave 0..3
    const int acol = w16 + (tyw << 2);

    float acc[4][4];
#pragma unroll
    for (int i = 0; i < 4; i++)
#pragma unroll
        for (int j = 0; j < 4; j++) acc[i][j] = 0.f;

    for (int seg = 0; seg < 9; seg++) {
        const float* __restrict__ Wseg = (seg == 0) ? root : (weight + (size_t)(seg - 1) * (F * F));

        if (seg == 0) {
            // root: stage own-row x (transposed into As); all tiles full
            const float* rowp = x + (size_t)(node0 + sn) * F;
#pragma unroll
            for (int j = 0; j < 4; j++) {
                int kc = k0 + 16 * j;
                float4 vv = *(const float4*)(rowp + kc);
                As[kc + 0][sn] = vv.x;
                As[kc + 1][sn] = vv.y;
                As[kc + 2][sn] = vv.z;
                As[kc + 3][sn] = vv.w;
            }
        } else {
            // mean-gather this wave's 16 nodes for relation seg-1
            const int key = ((seg - 1) << 5) | sn;
            const int beg = kstart[key];
            const int end = kstart[key + 1];   // prefix property: next start
            float4 a0v = make_float4(0.f, 0.f, 0.f, 0.f);
            float4 a1v = a0v, a2v = a0v, a3v = a0v;
            int i = beg;
            // 4-edge unroll: 16 independent row-loads in flight
            for (; i + 4 <= end; i += 4) {
                const float* r0 = x + (size_t)slist[i]     * F + k0;
                const float* r1 = x + (size_t)slist[i + 1] * F + k0;
                const float* r2 = x + (size_t)slist[i + 2] * F + k0;
                const float* r3 = x + (size_t)slist[i + 3] * F + k0;
                float4 u00 = *(const float4*)(r0);      float4 u01 = *(const float4*)(r1);
                float4 u02 = *(const float4*)(r2);      float4 u03 = *(const float4*)(r3);
                float4 u10 = *(const float4*)(r0 + 16); float4 u11 = *(const float4*)(r1 + 16);
                float4 u12 = *(const float4*)(r2 + 16); float4 u13 = *(const float4*)(r3 + 16);
                float4 u20 = *(const float4*)(r0 + 32); float4 u21 = *(const float4*)(r1 + 32);
                float4 u22 = *(const float4*)(r2 + 32); float4 u23 = *(const float4*)(r3 + 32);
                float4 u30 = *(const float4*)(r0 + 48); float4 u31 = *(const float4*)(r1 + 48);
                float4 u32_ = *(const float4*)(r2 + 48); float4 u33 = *(const float4*)(r3 + 48);
                a0v.x += (u00.x + u01.x) + (u02.x + u03.x);
                a0v.y += (u00.y + u01.y) + (u02.y + u03.y);
                a0v.z += (u00.z + u01.z) + (u02.z + u03.z);
                a0v.w += (u00.w + u01.w) + (u02.w + u03.w);
                a1v.x += (u10.x + u11.x) + (u12.x + u13.x);
                a1v.y += (u10.y + u11.y) + (u12.y + u13.y);
                a1v.z += (u10.z + u11.z) + (u12.z + u13.z);
                a1v.w += (u10.w + u11.w) + (u12.w + u13.w);
                a2v.x += (u20.x + u21.x) + (u22.x + u23.x);
                a2v.y += (u20.y + u21.y) + (u22.y + u23.y);
                a2v.z += (u20.z + u21.z) + (u22.z + u23.z);
                a2v.w += (u20.w + u21.w) + (u22.w + u23.w);
                a3v.x += (u30.x + u31.x) + (u32_.x + u33.x);
                a3v.y += (u30.y + u31.y) + (u32_.y + u33.y);
                a3v.z += (u30.z + u31.z) + (u32_.z + u33.z);
                a3v.w += (u30.w + u31.w) + (u32_.w + u33.w);
            }
            if (i + 2 <= end) {
                const float* r0 = x + (size_t)slist[i]     * F + k0;
                const float* r1 = x + (size_t)slist[i + 1] * F + k0;
                float4 u00 = *(const float4*)(r0);      float4 u01 = *(const float4*)(r1);
                float4 u10 = *(const float4*)(r0 + 16); float4 u11 = *(const float4*)(r1 + 16);
                float4 u20 = *(const float4*)(r0 + 32); float4 u21 = *(const float4*)(r1 + 32);
                float4 u30 = *(const float4*)(r0 + 48); float4 u31 = *(const float4*)(r1 + 48);
                a0v.x += u00.x + u01.x; a0v.y += u00.y + u01.y;
                a0v.z += u00.z + u01.z; a0v.w += u00.w + u01.w;
                a1v.x += u10.x + u11.x; a1v.y += u10.y + u11.y;
                a1v.z += u10.z + u11.z; a1v.w += u10.w + u11.w;
                a2v.x += u20.x + u21.x; a2v.y += u20.y + u21.y;
                a2v.z += u20.z + u21.z; a2v.w += u20.w + u21.w;
                a3v.x += u30.x + u31.x; a3v.y += u30.y + u31.y;
                a3v.z += u30.z + u31.z; a3v.w += u30.w + u31.w;
                i += 2;
            }
            if (i < end) {
                const float* r0 = x + (size_t)slist[i] * F + k0;
                float4 u0 = *(const float4*)(r0);
                float4 u1 = *(const float4*)(r0 + 16);
                float4 u2 = *(const float4*)(r0 + 32);
                float4 u3 = *(const float4*)(r0 + 48);
                a0v.x += u0.x; a0v.y += u0.y; a0v.z += u0.z; a0v.w += u0.w;
                a1v.x += u1.x; a1v.y += u1.y; a1v.z += u1.z; a1v.w += u1.w;
                a2v.x += u2.x; a2v.y += u2.y; a2v.z += u2.z; a2v.w += u2.w;
                a3v.x += u3.x; a3v.y += u3.y; a3v.z += u3.z; a3v.w += u3.w;
            }
            const float scl = 1.0f / (float)max(end - beg, 1);
            As[k0 +  0][sn] = a0v.x * scl; As[k0 +  1][sn] = a0v.y * scl;
            As[k0 +  2][sn] = a0v.z * scl; As[k0 +  3][sn] = a0v.w * scl;
            As[k0 + 16][sn] = a1v.x * scl; As[k0 + 17][sn] = a1v.y * scl;
            As[k0 + 18][sn] = a1v.z * scl; As[k0 + 19][sn] = a1v.w * scl;
            As[k0 + 32][sn] = a2v.x * scl; As[k0 + 33][sn] = a2v.y * scl;
            As[k0 + 34][sn] = a2v.z * scl; As[k0 + 35][sn] = a2v.w * scl;
            As[k0 + 48][sn] = a3v.x * scl; As[k0 + 49][sn] = a3v.y * scl;
            As[k0 + 50][sn] = a3v.z * scl; As[k0 + 51][sn] = a3v.w * scl;
        }

        // wave-local GEMM: reads only this wave's 16 columns (same-wave LDS
        // RAW, in-order -> no barrier). b rows straight from global (L1-hot).
#pragma unroll 8
        for (int k = 0; k < 64; k++) {
            float4 a = *(const float4*)&As[k][acol];
            float4 b = *(const float4*)(Wseg + (k << 6) + (tx << 2));
            acc[0][0] = fmaf(a.x, b.x, acc[0][0]);
            acc[0][1] = fmaf(a.x, b.y, acc[0][1]);
            acc[0][2] = fmaf(a.x, b.z, acc[0][2]);
            acc[0][3] = fmaf(a.x, b.w, acc[0][3]);
            acc[1][0] = fmaf(a.y, b.x, acc[1][0]);
            acc[1][1] = fmaf(a.y, b.y, acc[1][1]);
            acc[1][2] = fmaf(a.y, b.z, acc[1][2]);
            acc[1][3] = fmaf(a.y, b.w, acc[1][3]);
            acc[2][0] = fmaf(a.z, b.x, acc[2][0]);
            acc[2][1] = fmaf(a.z, b.y, acc[2][1]);
            acc[2][2] = fmaf(a.z, b.z, acc[2][2]);
            acc[2][3] = fmaf(a.z, b.w, acc[2][3]);
            acc[3][0] = fmaf(a.w, b.x, acc[3][0]);
            acc[3][1] = fmaf(a.w, b.y, acc[3][1]);
            acc[3][2] = fmaf(a.w, b.z, acc[3][2]);
            acc[3][3] = fmaf(a.w, b.w, acc[3][3]);
        }
    }

    // epilogue: + bias, coalesced float4 stores (wave-private, no barrier)
    float4 bv = *(const float4*)(bias + (tx << 2));
#pragma unroll
    for (int i = 0; i < 4; i++) {
        int node = node0 + w16 + (tyw << 2) + i;   // always < NN (NN%32==0)
        float4 o = make_float4(acc[i][0] + bv.x, acc[i][1] + bv.y,
                               acc[i][2] + bv.z, acc[i][3] + bv.w);
        *(float4*)(out + (size_t)node * F + (tx << 2)) = o;
    }
}

extern "C" void kernel_launch(void* const* d_in, const int* in_sizes, int n_in,
                              void* d_out, int out_size, void* d_ws, size_t ws_size,
                              hipStream_t stream) {
    const float* x    = (const float*)d_in[0];
    const int*   ei   = (const int*)d_in[1];
    const int*   et   = (const int*)d_in[2];
    const float* wgt  = (const float*)d_in[3];
    const float* root = (const float*)d_in[4];
    const float* bias = (const float*)d_in[5];
    float*       out  = (float*)d_out;

    int*      cursors = (int*)d_ws;                                   // [128]
    unsigned* runsd   = (unsigned*)((char*)d_ws + 512);               // [784*32]
    unsigned* stag4   = (unsigned*)((char*)d_ws + 512 + 100352);      // 14.5 MB
    unsigned* packed4 = stag4 + (size_t)NCB * CAPC;                   // 14.5 MB

    init_kernel<<<1, 128, 0, stream>>>(cursors);
    binA_kernel<<<NE / CHUNKA, 256, 0, stream>>>(ei, ei + NE, et, cursors, stag4);
    binB_kernel<<<NCB * 8, 256, 0, stream>>>(stag4, cursors, packed4, runsd);
    fused_kernel<<<NT, 128, 0, stream>>>(x, packed4, runsd, wgt, root, bias, out);
}